// Round 7
// baseline (411.446 us; speedup 1.0000x reference)
//
#include <hip/hip_runtime.h>
#include <hip/hip_bf16.h>
#include <math.h>

#define B_ 2
#define L_ 2048
#define D_ 2048
#define H_ 16
#define HD_ 128
#define E_ (B_*L_*D_)   // 8388608
#define W_ (D_*D_)      // 4194304

typedef __bf16 bf16;
typedef __bf16 bf16x8 __attribute__((ext_vector_type(8)));
typedef __bf16 bf16x4 __attribute__((ext_vector_type(4)));
typedef float  f32x4  __attribute__((ext_vector_type(4)));

// async global->LDS, 16B per lane; lds ptr must be wave-uniform
#define GLL16(gp_, lp_) __builtin_amdgcn_global_load_lds( \
    (const __attribute__((address_space(1))) void*)(gp_), \
    (__attribute__((address_space(3))) void*)(lp_), 16, 0, 0)

#define BARRIER() do { asm volatile("" ::: "memory"); \
    __builtin_amdgcn_s_barrier(); \
    asm volatile("" ::: "memory"); } while (0)

#define WAITN(N) asm volatile("s_waitcnt vmcnt(" #N ")" ::: "memory")

// ---------------- prep: all f32->bf16 converts + rope table, one launch ----------------
__global__ void prep(const float* __restrict__ xq, const float* __restrict__ xkv,
                     const float* __restrict__ wq, const float* __restrict__ wk,
                     const float* __restrict__ wv, const float* __restrict__ wo,
                     bf16* __restrict__ xqb, bf16* __restrict__ xkvb,
                     bf16* __restrict__ wqb, bf16* __restrict__ wkb,
                     bf16* __restrict__ wvb, bf16* __restrict__ wob,
                     float* __restrict__ ct, float* __restrict__ st) {
  int g = blockIdx.x;
  if (g < 16384) {
    const float* s = (g < 8192) ? xq : xkv;
    bf16* d = (g < 8192) ? xqb : xkvb;
    int i = ((g & 8191) * 256 + threadIdx.x) * 4;
    f32x4 v = *reinterpret_cast<const f32x4*>(s + i);
    bf16x4 o; o[0]=(bf16)v[0]; o[1]=(bf16)v[1]; o[2]=(bf16)v[2]; o[3]=(bf16)v[3];
    *reinterpret_cast<bf16x4*>(d + i) = o;
  } else if (g < 32768) {
    int gg = g - 16384;
    int which = gg >> 12;
    const float* s = (which==0)?wq:(which==1)?wk:(which==2)?wv:wo;
    bf16* d = (which==0)?wqb:(which==1)?wkb:(which==2)?wvb:wob;
    int i = ((gg & 4095) * 256 + threadIdx.x) * 4;
    f32x4 v = *reinterpret_cast<const f32x4*>(s + i);
    bf16x4 o; o[0]=(bf16)v[0]; o[1]=(bf16)v[1]; o[2]=(bf16)v[2]; o[3]=(bf16)v[3];
    *reinterpret_cast<bf16x4*>(d + i) = o;
  } else {
    int idx = (g - 32768) * 256 + threadIdx.x;   // < 131072 = 2048*64
    int t = idx >> 6, i = idx & 63;
    float inv = powf(10000.0f, -2.0f * (float)i / 128.0f);
    float f = (float)t * inv;
    ct[t * 64 + i] = cosf(f);
    st[t * 64 + i] = sinf(f);
  }
}

// ---------------- fused QKV GEMM + RoPE epilogue + V-transpose epilogue ----------------
__global__ __launch_bounds__(256, 4) void gemm_qkv(
    const bf16* __restrict__ xq, const bf16* __restrict__ xkv,
    const bf16* __restrict__ wq, const bf16* __restrict__ wk, const bf16* __restrict__ wv,
    const float* __restrict__ ct, const float* __restrict__ st,
    bf16* __restrict__ Qo, bf16* __restrict__ Ko, bf16* __restrict__ Vt) {
  __shared__ bf16 As[128 * 64];
  __shared__ bf16 Bs[128 * 64];
  const int tid = threadIdx.x;
  const int lane = tid & 63;
  const int w = tid >> 6;
  const int l15 = lane & 15, lg = lane >> 4;
  const int which = blockIdx.x >> 4;            // 0=Q, 1=K, 2=V
  const int n0 = (blockIdx.x & 15) * 128;
  const int m0 = blockIdx.y * 128;
  const int wm = (w >> 1) * 64, wn = (w & 1) * 64;
  const bf16* A  = (which == 0) ? xq : xkv;
  const bf16* Wt = (which == 0) ? wq : ((which == 1) ? wk : wv);

  int rowS[4], schS[4];
#pragma unroll
  for (int s = 0; s < 4; ++s) {
    int cl = s * 256 + tid;
    rowS[s] = cl >> 3;
    schS[s] = ((cl & 7) ^ ((cl >> 3) & 7)) << 3;
  }

  f32x4 acc[4][4];
#pragma unroll
  for (int m = 0; m < 4; ++m)
#pragma unroll
    for (int n = 0; n < 4; ++n) acc[m][n] = (f32x4){0.f, 0.f, 0.f, 0.f};

  for (int kt = 0; kt < D_; kt += 64) {
    __syncthreads();
#pragma unroll
    for (int s = 0; s < 4; ++s) {
      GLL16(A  + (size_t)(m0 + rowS[s]) * D_ + kt + schS[s], As + s * 2048 + w * 512);
      GLL16(Wt + (size_t)(n0 + rowS[s]) * D_ + kt + schS[s], Bs + s * 2048 + w * 512);
    }
    __syncthreads();
#pragma unroll
    for (int kk = 0; kk < 64; kk += 32) {
      bf16x8 af[4], bfr[4];
#pragma unroll
      for (int m = 0; m < 4; ++m)
        af[m] = *reinterpret_cast<const bf16x8*>(
            As + (wm + m * 16 + l15) * 64 + ((((kk >> 3) + lg) ^ (l15 & 7)) << 3));
#pragma unroll
      for (int n = 0; n < 4; ++n)
        bfr[n] = *reinterpret_cast<const bf16x8*>(
            Bs + (wn + n * 16 + l15) * 64 + ((((kk >> 3) + lg) ^ (l15 & 7)) << 3));
#pragma unroll
      for (int m = 0; m < 4; ++m)
#pragma unroll
        for (int n = 0; n < 4; ++n)
          acc[m][n] = __builtin_amdgcn_mfma_f32_16x16x32_bf16(af[m], bfr[n], acc[m][n], 0, 0, 0);
    }
  }

  if (which == 2) {
    const int b = m0 >> 11;
    const int l0b = (m0 & 2047) + wm + lg * 4;
#pragma unroll
    for (int m = 0; m < 4; ++m) {
      int l0 = l0b + m * 16;
#pragma unroll
      for (int n = 0; n < 4; ++n) {
        int c = n0 + wn + n * 16 + l15;
        int hd = (b * 16 + (c >> 7)) * 128 + (c & 127);
        bf16x4 o;
        o[0] = (bf16)acc[m][n][0]; o[1] = (bf16)acc[m][n][1];
        o[2] = (bf16)acc[m][n][2]; o[3] = (bf16)acc[m][n][3];
        *reinterpret_cast<bf16x4*>(Vt + (size_t)hd * L_ + l0) = o;
      }
    }
  } else {
    bf16* Out = which ? Ko : Qo;
    const bool odd = (l15 & 1);
#pragma unroll
    for (int m = 0; m < 4; ++m) {
      int row = m0 + wm + m * 16 + lg * 4;
      int l = row & 2047;
#pragma unroll
      for (int n = 0; n < 4; ++n) {
        int c = n0 + wn + n * 16 + l15;
        int i = (c & 127) >> 1;
#pragma unroll
        for (int r = 0; r < 4; ++r) {
          float own = acc[m][n][r];
          float prt = __shfl_xor(own, 1, 64);
          float cc = ct[(size_t)(l + r) * 64 + i];
          float ss = st[(size_t)(l + r) * 64 + i];
          float res = odd ? (prt * ss + own * cc) : (own * cc - prt * ss);
          Out[(size_t)(row + r) * D_ + c] = (bf16)res;
        }
      }
    }
  }
}

// ---------------- GEMM: C[M,N] = A[M,K] @ Bw[N,K]^T (m97 structure, f32 out) ----------------
__global__ __launch_bounds__(256, 4) void gemm_bt(const bf16* __restrict__ A,
                                                  const bf16* __restrict__ Bw,
                                                  float* __restrict__ Cout,
                                                  int M, int N, int K) {
  __shared__ bf16 As[128 * 64];
  __shared__ bf16 Bs[128 * 64];
  const int tid = threadIdx.x;
  const int lane = tid & 63;
  const int w = tid >> 6;
  const int l15 = lane & 15, lg = lane >> 4;
  const int m0 = blockIdx.y * 128, n0 = blockIdx.x * 128;
  const int wm = (w >> 1) * 64, wn = (w & 1) * 64;

  int rowS[4], schS[4];
#pragma unroll
  for (int s = 0; s < 4; ++s) {
    int cl = s * 256 + tid;
    rowS[s] = cl >> 3;
    schS[s] = ((cl & 7) ^ ((cl >> 3) & 7)) << 3;
  }

  f32x4 acc[4][4];
#pragma unroll
  for (int m = 0; m < 4; ++m)
#pragma unroll
    for (int n = 0; n < 4; ++n) acc[m][n] = (f32x4){0.f, 0.f, 0.f, 0.f};

  for (int kt = 0; kt < K; kt += 64) {
    __syncthreads();
#pragma unroll
    for (int s = 0; s < 4; ++s) {
      GLL16(A  + (size_t)(m0 + rowS[s]) * K + kt + schS[s], As + s * 2048 + w * 512);
      GLL16(Bw + (size_t)(n0 + rowS[s]) * K + kt + schS[s], Bs + s * 2048 + w * 512);
    }
    __syncthreads();
#pragma unroll
    for (int kk = 0; kk < 64; kk += 32) {
      bf16x8 af[4], bfr[4];
#pragma unroll
      for (int m = 0; m < 4; ++m)
        af[m] = *reinterpret_cast<const bf16x8*>(
            As + (wm + m * 16 + l15) * 64 + ((((kk >> 3) + lg) ^ (l15 & 7)) << 3));
#pragma unroll
      for (int n = 0; n < 4; ++n)
        bfr[n] = *reinterpret_cast<const bf16x8*>(
            Bs + (wn + n * 16 + l15) * 64 + ((((kk >> 3) + lg) ^ (l15 & 7)) << 3));
#pragma unroll
      for (int m = 0; m < 4; ++m)
#pragma unroll
        for (int n = 0; n < 4; ++n)
          acc[m][n] = __builtin_amdgcn_mfma_f32_16x16x32_bf16(af[m], bfr[n], acc[m][n], 0, 0, 0);
    }
  }
#pragma unroll
  for (int m = 0; m < 4; ++m) {
    int orow = m0 + wm + m * 16 + lg * 4;
#pragma unroll
    for (int n = 0; n < 4; ++n) {
      int col = n0 + wn + n * 16 + l15;
#pragma unroll
      for (int r = 0; r < 4; ++r)
        Cout[(size_t)(orow + r) * N + col] = acc[m][n][r];
    }
  }
}

// ---------------- fused causal attention: 2 barriers/iter, V dbuf, K single ----------------
// Block = one 128-row q-tile (4 waves x 32 rows), paired remap, 2 blocks/CU.
__global__ __launch_bounds__(256, 2) void attn_fused(const bf16* __restrict__ Qb,
                                                     const bf16* __restrict__ Kb,
                                                     const bf16* __restrict__ Vt,
                                                     float* __restrict__ attn,
                                                     bf16* __restrict__ Oh) {
  __shared__ bf16 Klds[64 * 128];      // 16 KB: K (pass2); K-buf0 (pass1)
  __shared__ bf16 Vlds[2][128 * 64];   // 32 KB: V dbuf (pass2); Vlds[0] = K-buf1 (pass1)
  __shared__ bf16 Plds[4][32][68];     // 17 KB

  const int tid = threadIdx.x;
  const int w = tid >> 6, lane = tid & 63;
  const int l15 = lane & 15, lg = lane >> 4;

  // pair (tile, bh<16) with (15-tile, bh>=16) at dispatch distance 256
  int g = blockIdx.x + 16 * blockIdx.y;
  int tq, bh;
  if (g < 256) { tq = g & 15;  bh = g >> 4; }
  else { int h2 = g - 256; tq = 15 - (h2 & 15); bh = 16 + (h2 >> 4); }
  const int b = bh >> 4, h = bh & 15;

  const int q0w = tq * 128 + w * 32;
  const int ntW = (q0w >> 6) + 1;           // groups this wave computes
  const int ntB = 2 * tq + 2;               // block loop trip count
  const float sc2 = 0.08838834764831845f * 1.44269504088896f;

  const bf16* kb = Kb + ((size_t)b * L_) * D_ + h * HD_;
  const bf16* vb = Vt + (size_t)bh * HD_ * L_;
  float* arow = attn + ((size_t)bh * L_ + q0w) * L_;

  bf16x8 qf[2][4];
#pragma unroll
  for (int qc = 0; qc < 2; ++qc) {
    const bf16* qrow = Qb + ((size_t)b * L_ + q0w + qc * 16 + l15) * D_ + h * HD_;
#pragma unroll
    for (int c = 0; c < 4; ++c)
      qf[qc][c] = *reinterpret_cast<const bf16x8*>(qrow + c * 32 + lg * 8);
  }

  // staging lane constants: 4 calls each (256 threads)
  int rK[4], sK[4], rV[4], sV[4];
#pragma unroll
  for (int s = 0; s < 4; ++s) {
    int ck = s * 256 + tid;
    rK[s] = ck >> 4; sK[s] = ((ck & 15) ^ (rK[s] & 7)) << 3;
    rV[s] = ck >> 3; sV[s] = ((ck & 7) ^ (rV[s] & 7)) << 3;
  }

  auto stageKto = [&](int gp, bf16* dst) {
#pragma unroll
    for (int s = 0; s < 4; ++s)
      GLL16(kb + (size_t)(gp * 64 + rK[s]) * D_ + sK[s], dst + s * 2048 + w * 512);
  };
  auto stageV = [&](int gp, int buf) {
#pragma unroll
    for (int s = 0; s < 4; ++s)
      GLL16(vb + (size_t)rV[s] * L_ + gp * 64 + sV[s], &Vlds[buf][0] + s * 2048 + w * 512);
  };
  auto qkt = [&](const bf16* kl, f32x4 acc[2][4]) {
    __builtin_amdgcn_s_setprio(1);
#pragma unroll
    for (int c = 0; c < 4; ++c)
#pragma unroll
      for (int t = 0; t < 4; ++t) {
        bf16x8 kf = *reinterpret_cast<const bf16x8*>(
            kl + (t * 16 + l15) * 128 + ((((c << 2) + lg) ^ (l15 & 7)) << 3));
#pragma unroll
        for (int qc = 0; qc < 2; ++qc)
          acc[qc][t] = __builtin_amdgcn_mfma_f32_16x16x32_bf16(qf[qc][c], kf, acc[qc][t], 0, 0, 0);
      }
    __builtin_amdgcn_s_setprio(0);
  };
  auto zstore32 = [&](int gp) {
#pragma unroll
    for (int qc = 0; qc < 2; ++qc)
#pragma unroll
      for (int t = 0; t < 4; ++t)
#pragma unroll
        for (int r = 0; r < 4; ++r)
          arow[(size_t)(qc * 16 + lg * 4 + r) * L_ + gp * 64 + t * 16 + l15] = 0.f;
  };

  // ================= pass 1: row sums (K dbuf: Klds / Vlds[0]) =================
  float sum[2][4] = {{0.f,0.f,0.f,0.f},{0.f,0.f,0.f,0.f}};
  stageKto(0, Klds);
  for (int gp = 0; gp < ntB; ++gp) {
    BARRIER();                               // A: prev qkt reads done
    const bool hn = (gp + 1 < ntB);
    if (hn) stageKto(gp + 1, ((gp + 1) & 1) ? &Vlds[0][0] : Klds);
    // own K(gp) landed: queue = [K(gp)][prev zstores 0|32][K(gp+1) 4*hn]
    const bool pz = (gp > 0) && ((gp - 1) >= ntW);
    if (pz) { if (hn) WAITN(36); else WAITN(32); }
    else    { if (hn) WAITN(4);  else WAITN(0);  }
    BARRIER();                               // B: K(gp) visible to all
    if (gp < ntW) {
      f32x4 acc[2][4];
#pragma unroll
      for (int qc = 0; qc < 2; ++qc)
#pragma unroll
        for (int t = 0; t < 4; ++t) acc[qc][t] = (f32x4){0.f,0.f,0.f,0.f};
      qkt((gp & 1) ? &Vlds[0][0] : Klds, acc);
      if (gp < ntW - 1) {
#pragma unroll
        for (int qc = 0; qc < 2; ++qc)
#pragma unroll
          for (int t = 0; t < 4; ++t)
#pragma unroll
            for (int r = 0; r < 4; ++r)
              sum[qc][r] += exp2f(acc[qc][t][r] * sc2);
      } else {
#pragma unroll
        for (int qc = 0; qc < 2; ++qc)
#pragma unroll
          for (int t = 0; t < 4; ++t)
#pragma unroll
            for (int r = 0; r < 4; ++r) {
              int kc = gp * 64 + t * 16 + l15;
              int qr = q0w + qc * 16 + lg * 4 + r;
              sum[qc][r] += (kc <= qr) ? exp2f(acc[qc][t][r] * sc2) : 0.f;
            }
      }
    } else {
      zstore32(gp);
    }
  }
  float rinv[2][4];
#pragma unroll
  for (int qc = 0; qc < 2; ++qc)
#pragma unroll
    for (int r = 0; r < 4; ++r) {
      float s = sum[qc][r];
#pragma unroll
      for (int sh = 1; sh < 16; sh <<= 1)
        s += __shfl_xor(s, sh, 64);
      rinv[qc][r] = 1.0f / s;
    }

  // ================= pass 2: 2 barriers/iter, V dbuf =================
  f32x4 oacc[2][8];
#pragma unroll
  for (int qc = 0; qc < 2; ++qc)
#pragma unroll
    for (int i = 0; i < 8; ++i) oacc[qc][i] = (f32x4){0.f, 0.f, 0.f, 0.f};

  BARRIER();                                 // pass-1 LDS reads done everywhere
  stageKto(0, Klds);
  stageV(0, 0);
  for (int gp = 0; gp < ntB; ++gp) {
    // own K(gp) and V(gp) landed; stores(gp-1) (32) may remain in flight
    if (gp == 0) { WAITN(0); } else { WAITN(32); }
    BARRIER();                               // A: K(gp), V(gp) visible to all
    const bool act = gp < ntW;
    float pv[2][4][4];
    if (act) {
      f32x4 acc[2][4];
#pragma unroll
      for (int qc = 0; qc < 2; ++qc)
#pragma unroll
        for (int t = 0; t < 4; ++t) acc[qc][t] = (f32x4){0.f,0.f,0.f,0.f};
      qkt(Klds, acc);
      if (gp < ntW - 1) {
#pragma unroll
        for (int qc = 0; qc < 2; ++qc)
#pragma unroll
          for (int t = 0; t < 4; ++t)
#pragma unroll
            for (int r = 0; r < 4; ++r)
              pv[qc][t][r] = exp2f(acc[qc][t][r] * sc2) * rinv[qc][r];
      } else {
#pragma unroll
        for (int qc = 0; qc < 2; ++qc)
#pragma unroll
          for (int t = 0; t < 4; ++t)
#pragma unroll
            for (int r = 0; r < 4; ++r) {
              int kc = gp * 64 + t * 16 + l15;
              int qr = q0w + qc * 16 + lg * 4 + r;
              pv[qc][t][r] = (kc <= qr) ? exp2f(acc[qc][t][r] * sc2) * rinv[qc][r] : 0.f;
            }
      }
    }
    BARRIER();                               // B: all waves done reading Klds; PV(gp-1) done
    const bool hn = (gp + 1 < ntB);
    if (hn) { stageKto(gp + 1, Klds); stageV(gp + 1, (gp + 1) & 1); }
    if (act) {
#pragma unroll
      for (int qc = 0; qc < 2; ++qc)
#pragma unroll
        for (int t = 0; t < 4; ++t)
#pragma unroll
          for (int r = 0; r < 4; ++r)
            Plds[w][qc * 16 + lg * 4 + r][t * 16 + l15] = (bf16)pv[qc][t][r];
#pragma unroll
      for (int qc = 0; qc < 2; ++qc)
#pragma unroll
        for (int t = 0; t < 4; ++t)
#pragma unroll
          for (int r = 0; r < 4; ++r)
            arow[(size_t)(qc * 16 + lg * 4 + r) * L_ + gp * 64 + t * 16 + l15] = pv[qc][t][r];
      asm volatile("s_waitcnt lgkmcnt(0)" ::: "memory");
      __builtin_amdgcn_sched_barrier(0);
      bf16x8 pa[2][2];
#pragma unroll
      for (int qc = 0; qc < 2; ++qc)
#pragma unroll
        for (int ck = 0; ck < 2; ++ck)
          pa[qc][ck] = *reinterpret_cast<const bf16x8*>(&Plds[w][qc * 16 + l15][ck * 32 + lg * 8]);
      const bf16* vl = &Vlds[gp & 1][0];
      __builtin_amdgcn_s_setprio(1);
#pragma unroll
      for (int ck = 0; ck < 2; ++ck)
#pragma unroll
        for (int t8 = 0; t8 < 8; ++t8) {
          bf16x8 vf = *reinterpret_cast<const bf16x8*>(
              vl + (t8 * 16 + l15) * 64 + ((((ck << 2) + lg) ^ (l15 & 7)) << 3));
#pragma unroll
          for (int qc = 0; qc < 2; ++qc)
            oacc[qc][t8] = __builtin_amdgcn_mfma_f32_16x16x32_bf16(pa[qc][ck], vf, oacc[qc][t8], 0, 0, 0);
        }
      __builtin_amdgcn_s_setprio(0);
    } else {
      zstore32(gp);
    }
  }

  // tail zeros: cols [ntB*64, 2048) for this wave's 32 rows
  for (int gp2 = ntB; gp2 < 32; ++gp2) {
#pragma unroll
    for (int i = 0; i < 8; ++i)
      *reinterpret_cast<f32x4*>(arow + (size_t)(i * 4 + lg) * L_ + gp2 * 64 + l15 * 4)
          = (f32x4){0.f, 0.f, 0.f, 0.f};
  }

#pragma unroll
  for (int qc = 0; qc < 2; ++qc) {
    bf16* orow = Oh + ((size_t)b * L_ + q0w + qc * 16) * D_ + h * HD_;
#pragma unroll
    for (int t8 = 0; t8 < 8; ++t8)
#pragma unroll
      for (int r = 0; r < 4; ++r)
        orow[(size_t)(lg * 4 + r) * D_ + t8 * 16 + l15] = (bf16)oacc[qc][t8][r];
  }
}

// ---------------- host ----------------
extern "C" void kernel_launch(void* const* d_in, const int* in_sizes, int n_in,
                              void* d_out, int out_size, void* d_ws, size_t ws_size,
                              hipStream_t stream) {
  const float* x_q  = (const float*)d_in[0];
  const float* x_kv = (const float*)d_in[1];
  const float* w_q = (const float*)d_in[3];
  const float* w_k = (const float*)d_in[4];
  const float* w_v = (const float*)d_in[5];
  const float* w_o = (const float*)d_in[6];

  char* p = (char*)d_ws;
  auto alloc = [&](size_t bytes) { char* r = p; p += (bytes + 255) & ~(size_t)255; return r; };
  bf16* xq_b  = (bf16*)alloc((size_t)E_ * 2);
  bf16* xkv_b = (bf16*)alloc((size_t)E_ * 2);
  bf16* wq_b  = (bf16*)alloc((size_t)W_ * 2);
  bf16* wk_b  = (bf16*)alloc((size_t)W_ * 2);
  bf16* wv_b  = (bf16*)alloc((size_t)W_ * 2);
  bf16* wo_b  = (bf16*)alloc((size_t)W_ * 2);
  bf16* Qraw  = (bf16*)alloc((size_t)E_ * 2);
  bf16* Kraw  = (bf16*)alloc((size_t)E_ * 2);
  bf16* Vt    = (bf16*)alloc((size_t)E_ * 2);
  bf16* Oh    = (bf16*)alloc((size_t)E_ * 2);
  float* ct   = (float*)alloc((size_t)L_ * 64 * 4);
  float* st2  = (float*)alloc((size_t)L_ * 64 * 4);

  float* out0     = (float*)d_out;
  float* attn_out = out0 + E_;

  prep<<<33280, 256, 0, stream>>>(x_q, x_kv, w_q, w_k, w_v, w_o,
                                  xq_b, xkv_b, wq_b, wk_b, wv_b, wo_b, ct, st2);
  gemm_qkv<<<dim3(48, 32), 256, 0, stream>>>(xq_b, xkv_b, wq_b, wk_b, wv_b,
                                             ct, st2, Qraw, Kraw, Vt);
  attn_fused<<<dim3(16, 32), 256, 0, stream>>>(Qraw, Kraw, Vt, attn_out, Oh);
  gemm_bt<<<dim3(16, 32), 256, 0, stream>>>(Oh, wo_b, out0, B_*L_, D_, D_);
}